// Round 1
// baseline (175.065 us; speedup 1.0000x reference)
//
#include <hip/hip_runtime.h>

typedef float v4f __attribute__((ext_vector_type(4)));
typedef int   v4i __attribute__((ext_vector_type(4)));

#define BB 512
#define CC 3
#define TT 16384
#define NBLK 2048
#define NTHREADS (NBLK * 256)      // 524288 threads = one thread per 16-element chunk
#define CPR 1024                   // chunks per row (T/16); rows = 16 waves, waves never straddle rows
// partials (SoA in d_ws): [0..2047]=nll, [2048..4095]=ss, [4096..6143]=cnt
// penalized transitions (prev,next) in {(0,2),(2,1),(1,0)} -> 3*p+n in {2,7,3} -> mask 0x8C

__global__ __launch_bounds__(256, 4) void ce_trans_main(const float* __restrict__ logits,
                                                        const int* __restrict__ labels,
                                                        float* __restrict__ partials) {
    const int tid0 = blockIdx.x * 256 + threadIdx.x;
    const int lane = threadIdx.x & 63;
    const int b    = tid0 >> 10;          // 1024 chunks per row
    const int cr   = tid0 & 1023;         // chunk index within row

    const float* p0 = logits + (size_t)b * (CC * TT) + (cr << 4);
    const int*   pl = labels + (size_t)b * TT + (cr << 4);

    // ---- issue ALL loads upfront: 12 logit dwordx4 + 4 label dwordx4 (one 64B line per stream) ----
    v4f A[4], Bv[4], Cv[4];
    v4i Lv[4];
#pragma unroll
    for (int k = 0; k < 4; ++k) A[k]  = __builtin_nontemporal_load((const v4f*)p0 + k);
#pragma unroll
    for (int k = 0; k < 4; ++k) Bv[k] = __builtin_nontemporal_load((const v4f*)(p0 + TT) + k);
#pragma unroll
    for (int k = 0; k < 4; ++k) Cv[k] = __builtin_nontemporal_load((const v4f*)(p0 + 2 * TT) + k);
#pragma unroll
    for (int k = 0; k < 4; ++k) Lv[k] = __builtin_nontemporal_load((const v4i*)pl + k);

    // lane-63 boundary prefetch (next chunk's first element per class), issued EARLY so the
    // ~600-cycle latency hides under the vector loads + compute. Only 1 lane/wave, 1x per thread.
    const bool tail = (lane == 63) && (cr != 1023);
    float g0 = 0.f, g1 = 0.f, g2 = 0.f;
    if (tail) {
        g0 = __builtin_nontemporal_load(p0 + 16);
        g1 = __builtin_nontemporal_load(p0 + TT + 16);
        g2 = __builtin_nontemporal_load(p0 + 2 * TT + 16);
    }

    float nll = 0.f, ss = 0.f;
    int cnt = 0;

    float f00 = 0.f, f10 = 0.f, f20 = 0.f;   // this thread's first element (for left neighbor)
    int   am0 = 0;
    float pv0 = 0.f, pv1 = 0.f, pv2 = 0.f;   // rolling previous element
    int   pam = 0;

    // ---- 16 elements: argmax + nll; 15 internal smoothness/transition boundaries in-register ----
#pragma unroll
    for (int t = 0; t < 16; ++t) {
        const int k = t >> 2, j = t & 3;
        const float v0 = A[k][j], v1 = Bv[k][j], v2 = Cv[k][j];
        const int   lab = Lv[k][j];

        int idx = 0;
        float mx = v0;
        if (v1 > mx) { mx = v1; idx = 1; }    // strict > == first-occurrence argmax
        if (v2 > mx) { mx = v2; idx = 2; }

        const float e  = __expf(v0 - mx) + __expf(v1 - mx) + __expf(v2 - mx);
        const float xl = (lab == 0) ? v0 : ((lab == 1) ? v1 : v2);
        nll += mx + __logf(e) - xl;

        if (t == 0) {
            f00 = v0; f10 = v1; f20 = v2; am0 = idx;
        } else {
            const float d0 = v0 - pv0;
            const float d1 = v1 - pv1;
            const float d2 = v2 - pv2;
            ss += d0 * d0 + d1 * d1 + d2 * d2;
            cnt += (0x8C >> (3 * pam + idx)) & 1;
        }
        pv0 = v0; pv1 = v1; pv2 = v2; pam = idx;
    }

    // ---- single external boundary: next chunk's first element via shuffle (lanes 0..62) ----
    float xn0 = __shfl_down(f00, 1, 64);
    float xn1 = __shfl_down(f10, 1, 64);
    float xn2 = __shfl_down(f20, 1, 64);
    int   amn = __shfl_down(am0, 1, 64);
    if (tail) {
        xn0 = g0; xn1 = g1; xn2 = g2;
        int idx = 0;
        float mx = xn0;
        if (xn1 > mx) { mx = xn1; idx = 1; }
        if (xn2 > mx) { mx = xn2; idx = 2; }
        amn = idx;
    }
    if (cr != 1023) {                          // row end has no t+1 neighbor (only lane 63 can hit this)
        const float d0 = xn0 - pv0;
        const float d1 = xn1 - pv1;
        const float d2 = xn2 - pv2;
        ss += d0 * d0 + d1 * d1 + d2 * d2;
        cnt += (0x8C >> (3 * pam + amn)) & 1;
    }

    // ---- wave64 shuffle reduction ----
    float fcnt = (float)cnt;
#pragma unroll
    for (int off = 32; off > 0; off >>= 1) {
        nll  += __shfl_down(nll,  off, 64);
        ss   += __shfl_down(ss,   off, 64);
        fcnt += __shfl_down(fcnt, off, 64);
    }

    __shared__ float s_nll[4], s_ss[4], s_cnt[4];
    const int wave = threadIdx.x >> 6;
    if ((threadIdx.x & 63) == 0) { s_nll[wave] = nll; s_ss[wave] = ss; s_cnt[wave] = fcnt; }
    __syncthreads();
    if (threadIdx.x == 0) {
        partials[blockIdx.x]            = s_nll[0] + s_nll[1] + s_nll[2] + s_nll[3];
        partials[NBLK + blockIdx.x]     = s_ss[0]  + s_ss[1]  + s_ss[2]  + s_ss[3];
        partials[2 * NBLK + blockIdx.x] = s_cnt[0] + s_cnt[1] + s_cnt[2] + s_cnt[3];
    }
}

__global__ __launch_bounds__(256) void ce_trans_final(const float* __restrict__ partials,
                                                      float* __restrict__ out) {
    float sn = 0.f, st = 0.f, sc = 0.f;
    // each stream: 2048 floats = 512 float4; 256 threads x 2 float4
#pragma unroll
    for (int k = 0; k < 2; ++k) {
        const int i = k * 256 + threadIdx.x;
        const v4f n4 = *((const v4f*)partials + i);
        const v4f s4 = *((const v4f*)partials + 512 + i);
        const v4f c4 = *((const v4f*)partials + 1024 + i);
        sn += n4.x + n4.y + n4.z + n4.w;
        st += s4.x + s4.y + s4.z + s4.w;
        sc += c4.x + c4.y + c4.z + c4.w;
    }
#pragma unroll
    for (int off = 32; off > 0; off >>= 1) {
        sn += __shfl_down(sn, off, 64);
        st += __shfl_down(st, off, 64);
        sc += __shfl_down(sc, off, 64);
    }
    __shared__ float s_n[4], s_s[4], s_c[4];
    const int wave = threadIdx.x >> 6;
    if ((threadIdx.x & 63) == 0) { s_n[wave] = sn; s_s[wave] = st; s_c[wave] = sc; }
    __syncthreads();
    if (threadIdx.x == 0) {
        const float tn = s_n[0] + s_n[1] + s_n[2] + s_n[3];
        const float ts = s_s[0] + s_s[1] + s_s[2] + s_s[3];
        const float tc = s_c[0] + s_c[1] + s_c[2] + s_c[3];
        const float ce = tn / 8388608.0f;              // B*T
        const float sm = 0.01f * (ts / 25164288.0f);   // B*C*(T-1)
        const float tp = (tc > 0.5f) ? 0.1f : 0.0f;    // all table values are 1 => sum/count == 1
        out[0] = ce + sm + tp;
    }
}

extern "C" void kernel_launch(void* const* d_in, const int* in_sizes, int n_in,
                              void* d_out, int out_size, void* d_ws, size_t ws_size,
                              hipStream_t stream) {
    const float* logits = (const float*)d_in[0];
    const int*   labels = (const int*)d_in[1];
    float* out      = (float*)d_out;
    float* partials = (float*)d_ws;   // 3 * 2048 floats = 24 KB

    ce_trans_main<<<NBLK, 256, 0, stream>>>(logits, labels, partials);
    ce_trans_final<<<1, 256, 0, stream>>>(partials, out);
}

// Round 2
// 163.931 us; speedup vs baseline: 1.0679x; 1.0679x over previous
//
#include <hip/hip_runtime.h>

typedef float v4f __attribute__((ext_vector_type(4)));
typedef int   v4i __attribute__((ext_vector_type(4)));

#define BB 512
#define CC 3
#define TT 16384
#define NBLK 2048
#define NTHREADS (NBLK * 256)          // 524288 threads
#define NQUAD (BB * TT / 4)            // 2,097,152 quads
#define ITERS (NQUAD / NTHREADS)       // 4 quads per thread
// quad q = it*NTHREADS + tid0. NTHREADS = 128 rows x 4096 quads, so:
//   tq = tid0 & 4095 (iteration-invariant!), b = it*128 + (tid0>>12)
// partials (SoA in d_ws): [0..2047]=nll, [2048..4095]=ss, [4096..6143]=cnt
// penalized transitions (prev,next) in {(0,2),(2,1),(1,0)} -> 3*p+n in {2,7,3} -> mask 0x8C

__global__ __launch_bounds__(256) void ce_trans_main(const float* __restrict__ logits,
                                                     const int* __restrict__ labels,
                                                     float* __restrict__ partials) {
    const int tid0 = blockIdx.x * 256 + threadIdx.x;
    const int lane = threadIdx.x & 63;
    const int tq   = tid0 & 4095;          // same for all iterations
    const int b0   = tid0 >> 12;
    const bool tail  = (lane == 63) && (tq != 4095);
    const bool valid = (lane != 63) || (tq != 4095);

    float nll = 0.f, ss = 0.f;
    int cnt = 0;

    // 2-deep software pipeline state
    v4f A[2], Bv[2], Cv[2];
    v4i Lv[2];

    auto issue = [&](int it, int slot) {
        const int b = b0 + it * 128;
        const float* p0 = logits + (size_t)b * (CC * TT) + (tq << 2);
        A[slot]  = __builtin_nontemporal_load((const v4f*)p0);
        Bv[slot] = __builtin_nontemporal_load((const v4f*)(p0 + TT));
        Cv[slot] = __builtin_nontemporal_load((const v4f*)(p0 + 2 * TT));
        Lv[slot] = __builtin_nontemporal_load((const v4i*)(labels + (size_t)b * TT + (tq << 2)));
    };

    issue(0, 0);

    // ---- boundary prefetch, HOISTED: all 4 iterations' lane-63 neighbor elements are
    // address-known at entry (tq iteration-invariant). Issued once, latency hides under
    // the pipelined vector loads instead of stalling each compute() tail. ----
    float g0[ITERS], g1[ITERS], g2[ITERS];
    if (tail) {
#pragma unroll
        for (int it = 0; it < ITERS; ++it) {
            const float* p0 = logits + (size_t)(b0 + it * 128) * (CC * TT) + (tq << 2);
            g0[it] = p0[4];
            g1[it] = p0[TT + 4];
            g2[it] = p0[2 * TT + 4];
        }
    }

    auto compute = [&](int it, int slot) {
        const v4f a = A[slot], bq = Bv[slot], c = Cv[slot];
        const v4i l = Lv[slot];
        const float x0[4] = {a.x,  a.y,  a.z,  a.w};
        const float x1[4] = {bq.x, bq.y, bq.z, bq.w};
        const float x2[4] = {c.x,  c.y,  c.z,  c.w};
        const int  lab[4] = {l.x,  l.y,  l.z,  l.w};
        int am[4];

#pragma unroll
        for (int j = 0; j < 4; ++j) {
            const float v0 = x0[j], v1 = x1[j], v2 = x2[j];
            int idx = 0;
            float mx = v0;
            if (v1 > mx) { mx = v1; idx = 1; }   // strict > == first-occurrence argmax
            if (v2 > mx) { mx = v2; idx = 2; }
            am[j] = idx;
            const float e  = __expf(v0 - mx) + __expf(v1 - mx) + __expf(v2 - mx);
            const float xl = (lab[j] == 0) ? v0 : ((lab[j] == 1) ? v1 : v2);
            nll += mx + __logf(e) - xl;
        }

#pragma unroll
        for (int j = 0; j < 3; ++j) {
            const float d0 = x0[j + 1] - x0[j];
            const float d1 = x1[j + 1] - x1[j];
            const float d2 = x2[j + 1] - x2[j];
            ss += d0 * d0 + d1 * d1 + d2 * d2;
            cnt += (0x8C >> (3 * am[j] + am[j + 1])) & 1;
        }

        // boundary element t0+4 = neighbor lane's first element (waves never straddle rows:
        // one row = 4096 quads = 64 full waves)
        float xn0 = __shfl_down(x0[0], 1, 64);
        float xn1 = __shfl_down(x1[0], 1, 64);
        float xn2 = __shfl_down(x2[0], 1, 64);
        int   amn = __shfl_down(am[0], 1, 64);
        if (tail) {
            xn0 = g0[it]; xn1 = g1[it]; xn2 = g2[it];
            int idx = 0;
            float mx = xn0;
            if (xn1 > mx) { mx = xn1; idx = 1; }
            if (xn2 > mx) { mx = xn2; idx = 2; }
            amn = idx;
        }
        if (valid) {
            const float d0 = xn0 - x0[3];
            const float d1 = xn1 - x1[3];
            const float d2 = xn2 - x2[3];
            ss += d0 * d0 + d1 * d1 + d2 * d2;
            cnt += (0x8C >> (3 * am[3] + amn)) & 1;
        }
    };

#pragma unroll
    for (int it = 0; it < ITERS; ++it) {
        if (it + 1 < ITERS) issue(it + 1, (it + 1) & 1);
        compute(it, it & 1);
    }

    // wave64 shuffle reduction
    float fcnt = (float)cnt;
#pragma unroll
    for (int off = 32; off > 0; off >>= 1) {
        nll  += __shfl_down(nll,  off, 64);
        ss   += __shfl_down(ss,   off, 64);
        fcnt += __shfl_down(fcnt, off, 64);
    }

    __shared__ float s_nll[4], s_ss[4], s_cnt[4];
    const int wave = threadIdx.x >> 6;
    if ((threadIdx.x & 63) == 0) { s_nll[wave] = nll; s_ss[wave] = ss; s_cnt[wave] = fcnt; }
    __syncthreads();
    if (threadIdx.x == 0) {
        partials[blockIdx.x]            = s_nll[0] + s_nll[1] + s_nll[2] + s_nll[3];
        partials[NBLK + blockIdx.x]     = s_ss[0]  + s_ss[1]  + s_ss[2]  + s_ss[3];
        partials[2 * NBLK + blockIdx.x] = s_cnt[0] + s_cnt[1] + s_cnt[2] + s_cnt[3];
    }
}

__global__ __launch_bounds__(256) void ce_trans_final(const float* __restrict__ partials,
                                                      float* __restrict__ out) {
    float sn = 0.f, st = 0.f, sc = 0.f;
    // each stream: 2048 floats = 512 float4; 256 threads x 2 float4
#pragma unroll
    for (int k = 0; k < 2; ++k) {
        const int i = k * 256 + threadIdx.x;
        const v4f n4 = *((const v4f*)partials + i);
        const v4f s4 = *((const v4f*)partials + 512 + i);
        const v4f c4 = *((const v4f*)partials + 1024 + i);
        sn += n4.x + n4.y + n4.z + n4.w;
        st += s4.x + s4.y + s4.z + s4.w;
        sc += c4.x + c4.y + c4.z + c4.w;
    }
#pragma unroll
    for (int off = 32; off > 0; off >>= 1) {
        sn += __shfl_down(sn, off, 64);
        st += __shfl_down(st, off, 64);
        sc += __shfl_down(sc, off, 64);
    }
    __shared__ float s_n[4], s_s[4], s_c[4];
    const int wave = threadIdx.x >> 6;
    if ((threadIdx.x & 63) == 0) { s_n[wave] = sn; s_s[wave] = st; s_c[wave] = sc; }
    __syncthreads();
    if (threadIdx.x == 0) {
        const float tn = s_n[0] + s_n[1] + s_n[2] + s_n[3];
        const float ts = s_s[0] + s_s[1] + s_s[2] + s_s[3];
        const float tc = s_c[0] + s_c[1] + s_c[2] + s_c[3];
        const float ce = tn / 8388608.0f;              // B*T
        const float sm = 0.01f * (ts / 25164288.0f);   // B*C*(T-1)
        const float tp = (tc > 0.5f) ? 0.1f : 0.0f;    // all table values are 1 => sum/count == 1
        out[0] = ce + sm + tp;
    }
}

extern "C" void kernel_launch(void* const* d_in, const int* in_sizes, int n_in,
                              void* d_out, int out_size, void* d_ws, size_t ws_size,
                              hipStream_t stream) {
    const float* logits = (const float*)d_in[0];
    const int*   labels = (const int*)d_in[1];
    float* out      = (float*)d_out;
    float* partials = (float*)d_ws;   // 3 * 2048 floats = 24 KB

    ce_trans_main<<<NBLK, 256, 0, stream>>>(logits, labels, partials);
    ce_trans_final<<<1, 256, 0, stream>>>(partials, out);
}